// Round 14
// baseline (543.618 us; speedup 1.0000x reference)
//
#include <hip/hip_runtime.h>
#include <hip/hip_bf16.h>

// MultiheadBlockAttention: B=4, S=512, NB=32, D=512, H=8, dh=64.
// R14 = R13 (SMUL=2, launch_bounds(512,2), spill-free, 231us) with the
// compute phase given full scheduling freedom:
//   - k-loop FULLY unrolled (was unroll 4): compiler can hoist/pipeline all
//     32 weight loads per phase across MFMAs with counted vmcnt -- R13 had
//     ~136 unused unified regs; unroll-4 capped outstanding loads at 8 and
//     drained them per group (latency exposure was the remaining stall
//     candidate after occupancy/traffic/async-staging all proved null).
//   - s_setprio(1) around MFMA clusters (projection + attention): waves
//     drift into stage-vs-compute roles between barriers (m224/m191 regime).

#define NBD (32 * 512)
#define XH_STRIDE 260                   // shorts per half-row = 520 B
#define XH_BYTES (32 * XH_STRIDE * 2)   // 16640 B per (bs) half-slice

typedef __bf16 bf16x8 __attribute__((ext_vector_type(8)));
typedef float f32x16 __attribute__((ext_vector_type(16)));

__device__ __forceinline__ unsigned f2b(float f) {
  union { float f; unsigned u; } v;
  v.f = f;
  return (v.u + 0x7fffu + ((v.u >> 16) & 1u)) >> 16;
}

__device__ __forceinline__ f32x16 mfma32(uint4 a, uint4 b, f32x16 c) {
  union { uint4 u; bf16x8 v; } ua, ub;
  ua.u = a;
  ub.u = b;
  return __builtin_amdgcn_mfma_f32_32x32x16_bf16(ua.v, ub.v, c, 0, 0, 0);
}

// two ds_read_b64 (8-aligned base)
__device__ __forceinline__ uint4 ld_lds_64x2(const unsigned short* p, unsigned byteoff) {
  const char* c = (const char*)p;
  uint2 lo = *(const uint2*)(c + byteoff);
  uint2 hi = *(const uint2*)(c + byteoff + 8);
  uint4 r;
  r.x = lo.x; r.y = lo.y; r.z = hi.x; r.w = hi.y;
  return r;
}

// C/D packed frag -> A/B-frag k-slice [qb block]: cross-half exchange + select.
__device__ __forceinline__ uint4 frag_cd(const unsigned* CP, int qb, int half) {
  const unsigned s0 = __shfl_xor(CP[qb + 0], 32);
  const unsigned s1 = __shfl_xor(CP[qb + 1], 32);
  const unsigned s2 = __shfl_xor(CP[qb + 2], 32);
  const unsigned s3 = __shfl_xor(CP[qb + 3], 32);
  uint4 f;
  f.x = half ? s2 : CP[qb + 0];
  f.y = half ? s3 : CP[qb + 1];
  f.z = half ? CP[qb + 2] : s0;
  f.w = half ? CP[qb + 3] : s1;
  return f;
}

// Pack wq|wk|wv fragment-major bf16: uint4 index
//   m*32768 + tile*2048 + k*64 + half*32 + l31  holds W[tile*32+l31][k*16+half*8..+7]
__global__ void wconv_kernel(const float* __restrict__ wq,
                             const float* __restrict__ wk,
                             const float* __restrict__ wv,
                             uint4* __restrict__ out) {
  const int g = blockIdx.x * blockDim.x + threadIdx.x;  // 0..98303
  const int m = g >> 15;
  const int j = g & 32767;
  const int l31 = j & 31;
  const int half = (j >> 5) & 1;
  const int k = (j >> 6) & 31;
  const int tile = j >> 11;  // 0..15
  const float* src = (m == 0) ? wq : (m == 1) ? wk : wv;
  const float4* p = (const float4*)(src + (size_t)(tile * 32 + l31) * 512 + k * 16 + half * 8);
  float4 f0 = p[0], f1 = p[1];
  uint4 o;
  o.x = f2b(f0.x) | (f2b(f0.y) << 16);
  o.y = f2b(f0.z) | (f2b(f0.w) << 16);
  o.z = f2b(f1.x) | (f2b(f1.y) << 16);
  o.w = f2b(f1.z) | (f2b(f1.w) << 16);
  out[g] = o;
}

__global__ __launch_bounds__(512, 2)
void mhba_kernel(const float* __restrict__ q_in, const float* __restrict__ k_in,
                 const float* __restrict__ v_in, const float* __restrict__ mask,
                 const float* __restrict__ bq, const float* __restrict__ bk,
                 const float* __restrict__ bv,
                 const uint4* __restrict__ wpk,   // fragment-major bf16 weights
                 float* __restrict__ out_attn,    // [B,S,NB,D]
                 float* __restrict__ out_w) {     // [B,H,S,NB,NB]
  // Double-buffered half-tiles, both bs: [buf][bs j at j*XH_BYTES].
  __shared__ unsigned short Xs[2][2 * 32 * XH_STRIDE];  // 66560 B
  __shared__ __align__(16) char SCR[8][2][4352];        // 69632 B

  const int bs0 = blockIdx.x * 2;
  const int tid = threadIdx.x;  // 0..511
  const int lane = tid & 63;
  const int h = tid >> 6;       // wave == head
  const int l31 = lane & 31;
  const int half = lane >> 5;

  const float* srcs[3] = {k_in, q_in, v_in};  // m-order: K, Q, V

  unsigned QT[2][2][8], VP[2][2][8];  // [bs j][tile t][q]
  const unsigned abase = (unsigned)(l31 * (XH_STRIDE * 2) + half * 16);

  float4 st[8];  // raw in-flight staging regs (32) -- no dependent op until
                 // STAGE_WRITE, so loads overlap the 64-MFMA COMPUTE phase.

  // issue the 8 loads for (matrix M, feature-half H1), both bs; NO conversion
#define STAGE_LOAD(M, H1)                                                  \
  {                                                                        \
    _Pragma("unroll") for (int j = 0; j < 2; ++j) {                        \
      const float4* s4 = (const float4*)(srcs[M] + (size_t)(bs0 + j) * NBD);\
      _Pragma("unroll") for (int i = 0; i < 4; ++i) {                      \
        const int idx4 = i * 512 + tid;                                    \
        st[j * 4 + i] = s4[(idx4 >> 6) * 128 + (H1)*64 + (idx4 & 63)];     \
      }                                                                    \
    }                                                                      \
  }

  // convert + write staged regs into half-buffer P (both bs) -- after COMPUTE
#define STAGE_WRITE(P)                                                     \
  {                                                                        \
    _Pragma("unroll") for (int j = 0; j < 2; ++j) {                        \
      _Pragma("unroll") for (int i = 0; i < 4; ++i) {                      \
        const int idx4 = i * 512 + tid;                                    \
        const int n = idx4 >> 6, k4 = idx4 & 63;                           \
        float4 f = st[j * 4 + i];                                          \
        uint2 u;                                                           \
        u.x = f2b(f.x) | (f2b(f.y) << 16);                                 \
        u.y = f2b(f.z) | (f2b(f.w) << 16);                                 \
        *(uint2*)((char*)Xs[P] + (j * XH_BYTES + n * (XH_STRIDE * 2) + k4 * 8)) = u; \
      }                                                                    \
    }                                                                      \
  }

  // 16 k-steps from half-buffer P, FULLY unrolled: scheduler may hoist all
  // 32 weight loads (4 regs each) into the ~136-reg headroom and interleave
  // counted waits with the MFMAs. accJT: bs j, tile t.
#define COMPUTE_HALF(P, WSEL, H1, TRANSPOSED)                              \
  {                                                                        \
    const uint4* w0 = wpk + (WSEL)*32768 + (2 * h) * 2048 + (H1)*1024 +    \
                      half * 32 + l31;                                     \
    const uint4* w1 = w0 + 2048;                                           \
    __builtin_amdgcn_s_setprio(1);                                         \
    _Pragma("unroll") for (int k = 0; k < 16; ++k) {                       \
      uint4 b0 = w0[k * 64];                                               \
      uint4 b1 = w1[k * 64];                                               \
      uint4 a0 = ld_lds_64x2(Xs[P], abase + (unsigned)k * 32);             \
      uint4 a1 = ld_lds_64x2(Xs[P], XH_BYTES + abase + (unsigned)k * 32);  \
      if (TRANSPOSED) {                                                    \
        acc00 = mfma32(b0, a0, acc00);                                     \
        acc01 = mfma32(b1, a0, acc01);                                     \
        acc10 = mfma32(b0, a1, acc10);                                     \
        acc11 = mfma32(b1, a1, acc11);                                     \
      } else {                                                             \
        acc00 = mfma32(a0, b0, acc00);                                     \
        acc01 = mfma32(a0, b1, acc01);                                     \
        acc10 = mfma32(a1, b0, acc10);                                     \
        acc11 = mfma32(a1, b1, acc11);                                     \
      }                                                                    \
    }                                                                      \
    __builtin_amdgcn_s_setprio(0);                                         \
  }

#define RESET_ACCS                                                         \
  {                                                                        \
    _Pragma("unroll") for (int r = 0; r < 16; ++r) {                       \
      acc00[r] = 0.0f; acc01[r] = 0.0f; acc10[r] = 0.0f; acc11[r] = 0.0f;  \
    }                                                                      \
  }

  f32x16 acc00, acc01, acc10, acc11;
  RESET_ACCS;

  // ---------------- pipelined projections (async feature-split) -----------
  STAGE_LOAD(0, 0);
  STAGE_WRITE(0);
  __syncthreads();

  // ph0: K half0 from buf0 (NORMAL), stage K half1 -> buf1
  STAGE_LOAD(0, 1);
  COMPUTE_HALF(0, 1, 0, 0);
  STAGE_WRITE(1);
  __syncthreads();

  // ph1: K half1 from buf1 (NORMAL), stage Q half0 -> buf0
  STAGE_LOAD(1, 0);
  COMPUTE_HALF(1, 1, 1, 0);
  {  // K epilogue per bs (normal C/D: lane = feature col, regs = token rows)
    const float bc0 = bk[h * 64 + l31];
    const float bc1 = bk[h * 64 + 32 + l31];
#pragma unroll
    for (int j = 0; j < 2; ++j) {
      char* scr = &SCR[h][j][0];
#pragma unroll
      for (int r = 0; r < 16; ++r) {
        const int n = (r & 3) + 8 * (r >> 2) + 4 * half;
        const unsigned base = (unsigned)(n * 128);
        const unsigned sw = (unsigned)(n & 7) << 4;
        const float a0 = (j == 0) ? acc00[r] : acc10[r];
        const float a1 = (j == 0) ? acc01[r] : acc11[r];
        *(unsigned short*)(scr + ((base + l31 * 2) ^ sw)) =
            (unsigned short)f2b(a0 + bc0);
        *(unsigned short*)(scr + ((base + 64 + l31 * 2) ^ sw)) =
            (unsigned short)f2b(a1 + bc1);
      }
    }
    RESET_ACCS;
  }
  STAGE_WRITE(0);
  __syncthreads();

  // ph2: Q half0 from buf0 (TRANSPOSED), stage Q half1 -> buf1
  STAGE_LOAD(1, 1);
  COMPUTE_HALF(0, 0, 0, 1);
  STAGE_WRITE(1);
  __syncthreads();

  // ph3: Q half1 from buf1 (TRANSPOSED), stage V half0 -> buf0
  STAGE_LOAD(2, 0);
  COMPUTE_HALF(1, 0, 1, 1);
  {  // Q^T epilogue: lane = token, regs = features
#pragma unroll
    for (int q = 0; q < 8; ++q) {
      const int n0 = ((2 * q) & 3) + 8 * (q >> 1) + 4 * half;  // feature idx
      float2 b0 = *(const float2*)(bq + h * 64 + n0);
      float2 b1 = *(const float2*)(bq + h * 64 + 32 + n0);
      QT[0][0][q] = f2b(acc00[2 * q] + b0.x) | (f2b(acc00[2 * q + 1] + b0.y) << 16);
      QT[0][1][q] = f2b(acc01[2 * q] + b1.x) | (f2b(acc01[2 * q + 1] + b1.y) << 16);
      QT[1][0][q] = f2b(acc10[2 * q] + b0.x) | (f2b(acc10[2 * q + 1] + b0.y) << 16);
      QT[1][1][q] = f2b(acc11[2 * q] + b1.x) | (f2b(acc11[2 * q + 1] + b1.y) << 16);
    }
    RESET_ACCS;
  }
  STAGE_WRITE(0);
  __syncthreads();

  // ph4: V half0 from buf0 (NORMAL), stage V half1 -> buf1
  STAGE_LOAD(2, 1);
  COMPUTE_HALF(0, 2, 0, 0);
  STAGE_WRITE(1);
  __syncthreads();

  // ph5: V half1 from buf1 (NORMAL, no staging)
  COMPUTE_HALF(1, 2, 1, 0);
  {  // V epilogue: lane = feature col, regs = token rows
    const float bc0 = bv[h * 64 + l31];
    const float bc1 = bv[h * 64 + 32 + l31];
#pragma unroll
    for (int q = 0; q < 8; ++q) {
      VP[0][0][q] = f2b(acc00[2 * q] + bc0) | (f2b(acc00[2 * q + 1] + bc0) << 16);
      VP[0][1][q] = f2b(acc01[2 * q] + bc1) | (f2b(acc01[2 * q + 1] + bc1) << 16);
      VP[1][0][q] = f2b(acc10[2 * q] + bc0) | (f2b(acc10[2 * q + 1] + bc0) << 16);
      VP[1][1][q] = f2b(acc11[2 * q] + bc1) | (f2b(acc11[2 * q + 1] + bc1) << 16);
    }
  }

  // ---------------- attention per bs (barrier-free, per-wave; R10 verbatim)
#pragma unroll
  for (int j = 0; j < 2; ++j) {
    const int bsj = bs0 + j;
    char* scr = &SCR[h][j][0];

    // K A-frags from scratch
    uint4 KA[4];
#pragma unroll
    for (int kk = 0; kk < 4; ++kk) {
      const unsigned off =
          (unsigned)(l31 * 128 + kk * 32 + half * 16) ^ ((unsigned)(l31 & 7) << 4);
      KA[kk] = *(const uint4*)(scr + off);
    }

    // S^T = K * Q^T : lane = query n, regs = key m
    f32x16 lg;
#pragma unroll
    for (int r = 0; r < 16; ++r) lg[r] = 0.0f;
    __builtin_amdgcn_s_setprio(1);
#pragma unroll
    for (int kk = 0; kk < 4; ++kk) {
      uint4 qf = frag_cd(QT[j][kk >> 1], (kk & 1) * 4, half);
      lg = mfma32(KA[kk], qf, lg);
    }
    __builtin_amdgcn_s_setprio(0);

    // softmax over keys m, in place; additive mask
    const float* mrow = mask + (size_t)bsj * 32;
    float w[16];
#pragma unroll
    for (int q = 0; q < 8; ++q) {
      const int mm0 = ((2 * q) & 3) + 8 * (q >> 1) + 4 * half;
      float2 mk = *(const float2*)(mrow + mm0);
      w[2 * q] = lg[2 * q] * 0.125f + mk.x;
      w[2 * q + 1] = lg[2 * q + 1] * 0.125f + mk.y;
    }
    float mx = w[0];
#pragma unroll
    for (int r = 1; r < 16; ++r) mx = fmaxf(mx, w[r]);
    mx = fmaxf(mx, __shfl_xor(mx, 32));
    float ss = 0.0f;
#pragma unroll
    for (int r = 0; r < 16; ++r) {
      w[r] = __expf(w[r] - mx);
      ss += w[r];
    }
    ss += __shfl_xor(ss, 32);
    const float inv = __frcp_rn(ss);
#pragma unroll
    for (int r = 0; r < 16; ++r) w[r] *= inv;

    // pack P (lane = query n, reg pairs = key rows)
    unsigned PP[8];
#pragma unroll
    for (int q = 0; q < 8; ++q)
      PP[q] = f2b(w[2 * q]) | (f2b(w[2 * q + 1]) << 16);

    // out_w: transpose through scratch j (K-buf dead by data dependence)
    asm volatile("" ::: "memory");
    float* scrF = (float*)scr;  // 32 x 33 floats = 4224 B <= 4352
#pragma unroll
    for (int r = 0; r < 16; ++r) {
      const int mm = (r & 3) + 8 * (r >> 2) + 4 * half;
      scrF[l31 * 33 + mm] = w[r];  // [query n=l31][key mm]
    }
    const int b = bsj >> 9;
    const int s = bsj & 511;
    float* wout = out_w + ((size_t)((b * 8 + h) * 512 + s)) * 1024;
#pragma unroll
    for (int jj = 0; jj < 16; ++jj) {
      const int n = 2 * jj + half;
      wout[n * 32 + l31] = scrF[n * 33 + l31];
    }

    // O = P * V
    f32x16 o0, o1;
#pragma unroll
    for (int r = 0; r < 16; ++r) { o0[r] = 0.0f; o1[r] = 0.0f; }
    __builtin_amdgcn_s_setprio(1);
#pragma unroll
    for (int kk = 0; kk < 2; ++kk) {
      uint4 pa = frag_cd(PP, 4 * kk, half);
      uint4 vb0 = frag_cd(VP[j][0], 4 * kk, half);
      uint4 vb1 = frag_cd(VP[j][1], 4 * kk, half);
      o0 = mfma32(pa, vb0, o0);
      o1 = mfma32(pa, vb1, o1);
    }
    __builtin_amdgcn_s_setprio(0);

    // output: lane col d = t*32+l31 of head h, rows n in regs
    float* obase = out_attn + (size_t)bsj * NBD + h * 64 + l31;
#pragma unroll
    for (int r = 0; r < 16; ++r) {
      const int n = (r & 3) + 8 * (r >> 2) + 4 * half;
      obase[n * 512] = o0[r];
      obase[n * 512 + 32] = o1[r];
    }
  }
#undef STAGE_LOAD
#undef STAGE_WRITE
#undef COMPUTE_HALF
#undef RESET_ACCS
}

extern "C" void kernel_launch(void* const* d_in, const int* in_sizes, int n_in,
                              void* d_out, int out_size, void* d_ws, size_t ws_size,
                              hipStream_t stream) {
  const float* q    = (const float*)d_in[0];
  const float* k    = (const float*)d_in[1];
  const float* v    = (const float*)d_in[2];
  const float* mask = (const float*)d_in[3];
  const float* wq   = (const float*)d_in[4];
  const float* bq   = (const float*)d_in[5];
  const float* wk   = (const float*)d_in[6];
  const float* bk   = (const float*)d_in[7];
  const float* wv   = (const float*)d_in[8];
  const float* bv   = (const float*)d_in[9];

  uint4* wpk = (uint4*)d_ws;  // 3*32768 uint4 = 1.5 MB fragment-major weights
  float* out_attn = (float*)d_out;
  float* out_w = out_attn + (size_t)4 * 512 * 32 * 512;

  wconv_kernel<<<384, 256, 0, stream>>>(wq, wk, wv, wpk);
  mhba_kernel<<<1024, 512, 0, stream>>>(q, k, v, mask, bq, bk, bv, wpk,
                                        out_attn, out_w);
}

// Round 16
// 284.928 us; speedup vs baseline: 1.9079x; 1.9079x over previous
//
#include <hip/hip_runtime.h>
#include <hip/hip_bf16.h>

// MultiheadBlockAttention: B=4, S=512, NB=32, D=512, H=8, dh=64.
// R16 = R15 (wave specialization) with the PSTAGE OOB bug fixed: a half-tile
// is 2048 float4 (32 rows x 256 feats), so 256 producer threads stage 8
// float4 each (R15 staged 4x too many -> global OOB reads -> core dump).
// Structure: one WG = 768 threads = 12 waves per (b,s):
//   waves 0..7  = consumers (wave h == head h): weight loads (L2) + MFMA
//     -- homogeneous vmcnt queue, no HBM staging loads ahead of weights.
//   waves 8..11 = producers: X staging only (HBM float4 -> f2b -> ds_write).
// Producers fill buf B while consumers compute buf A; uniform __syncthreads()
// swaps buffers. launch_bounds(768,3): 170-reg cap, consumer peak ~140.

#define NBD (32 * 512)
#define XH_STRIDE 260                   // shorts per half-row = 520 B
#define XH_BYTES (32 * XH_STRIDE * 2)   // 16640 B per half-buffer

typedef __bf16 bf16x8 __attribute__((ext_vector_type(8)));
typedef float f32x16 __attribute__((ext_vector_type(16)));

__device__ __forceinline__ unsigned f2b(float f) {
  union { float f; unsigned u; } v;
  v.f = f;
  return (v.u + 0x7fffu + ((v.u >> 16) & 1u)) >> 16;
}

__device__ __forceinline__ f32x16 mfma32(uint4 a, uint4 b, f32x16 c) {
  union { uint4 u; bf16x8 v; } ua, ub;
  ua.u = a;
  ub.u = b;
  return __builtin_amdgcn_mfma_f32_32x32x16_bf16(ua.v, ub.v, c, 0, 0, 0);
}

// two ds_read_b64 (8-aligned base)
__device__ __forceinline__ uint4 ld_lds_64x2(const unsigned short* p, unsigned byteoff) {
  const char* c = (const char*)p;
  uint2 lo = *(const uint2*)(c + byteoff);
  uint2 hi = *(const uint2*)(c + byteoff + 8);
  uint4 r;
  r.x = lo.x; r.y = lo.y; r.z = hi.x; r.w = hi.y;
  return r;
}

// C/D packed frag -> A/B-frag k-slice [qb block]: cross-half exchange + select.
__device__ __forceinline__ uint4 frag_cd(const unsigned* CP, int qb, int half) {
  const unsigned s0 = __shfl_xor(CP[qb + 0], 32);
  const unsigned s1 = __shfl_xor(CP[qb + 1], 32);
  const unsigned s2 = __shfl_xor(CP[qb + 2], 32);
  const unsigned s3 = __shfl_xor(CP[qb + 3], 32);
  uint4 f;
  f.x = half ? s2 : CP[qb + 0];
  f.y = half ? s3 : CP[qb + 1];
  f.z = half ? CP[qb + 2] : s0;
  f.w = half ? CP[qb + 3] : s1;
  return f;
}

// Pack wq|wk|wv fragment-major bf16: uint4 index
//   m*32768 + tile*2048 + k*64 + half*32 + l31  holds W[tile*32+l31][k*16+half*8..+7]
__global__ void wconv_kernel(const float* __restrict__ wq,
                             const float* __restrict__ wk,
                             const float* __restrict__ wv,
                             uint4* __restrict__ out) {
  const int g = blockIdx.x * blockDim.x + threadIdx.x;  // 0..98303
  const int m = g >> 15;
  const int j = g & 32767;
  const int l31 = j & 31;
  const int half = (j >> 5) & 1;
  const int k = (j >> 6) & 31;
  const int tile = j >> 11;  // 0..15
  const float* src = (m == 0) ? wq : (m == 1) ? wk : wv;
  const float4* p = (const float4*)(src + (size_t)(tile * 32 + l31) * 512 + k * 16 + half * 8);
  float4 f0 = p[0], f1 = p[1];
  uint4 o;
  o.x = f2b(f0.x) | (f2b(f0.y) << 16);
  o.y = f2b(f0.z) | (f2b(f0.w) << 16);
  o.z = f2b(f1.x) | (f2b(f1.y) << 16);
  o.w = f2b(f1.z) | (f2b(f1.w) << 16);
  out[g] = o;
}

__global__ __launch_bounds__(768, 3)
void mhba_kernel(const float* __restrict__ q_in, const float* __restrict__ k_in,
                 const float* __restrict__ v_in, const float* __restrict__ mask,
                 const float* __restrict__ bq, const float* __restrict__ bk,
                 const float* __restrict__ bv,
                 const uint4* __restrict__ wpk,   // fragment-major bf16 weights
                 float* __restrict__ out_attn,    // [B,S,NB,D]
                 float* __restrict__ out_w) {     // [B,H,S,NB,NB]
  __shared__ unsigned short Xs[2][32 * XH_STRIDE];  // 2 x 16640 B half-buffers
  __shared__ __align__(16) char SCR[8][4352];       // 34816 B per-head scratch

  const int bs = blockIdx.x;    // b = bs>>9, s = bs&511
  const int tid = threadIdx.x;  // 0..767
  const int lane = tid & 63;
  const int wave = tid >> 6;    // 0..11
  const int l31 = lane & 31;
  const int half = lane >> 5;
  const bool prod = (wave >= 8);
  const int h = wave;           // consumer: head h (0..7)
  const int pid = tid - 512;    // producer thread id (0..255)

  unsigned QT[2][8], VP[2][8];
  const unsigned abase = (unsigned)(l31 * (XH_STRIDE * 2) + half * 16);

  // producer: stage (matrix SRC, feature-half H1) -> half-buffer P.
  // Half-tile = 2048 float4 (32 rows x 64 float4); 256 producer threads x
  // 8 float4 each. Load all 8 (st[8]=32 regs), then convert+write.
#define PSTAGE(SRC, H1, P)                                                 \
  {                                                                        \
    const float4* s4 = (const float4*)((SRC) + (size_t)bs * NBD);          \
    float4 st[8];                                                          \
    _Pragma("unroll") for (int ii = 0; ii < 8; ++ii) {                     \
      const int idx4 = ii * 256 + pid;                                     \
      st[ii] = s4[(idx4 >> 6) * 128 + (H1)*64 + (idx4 & 63)];              \
    }                                                                      \
    _Pragma("unroll") for (int ii = 0; ii < 8; ++ii) {                     \
      const int idx4 = ii * 256 + pid;                                     \
      const int n = idx4 >> 6, k4 = idx4 & 63;                             \
      uint2 u;                                                             \
      u.x = f2b(st[ii].x) | (f2b(st[ii].y) << 16);                         \
      u.y = f2b(st[ii].z) | (f2b(st[ii].w) << 16);                         \
      *(uint2*)((char*)Xs[P] + (n * (XH_STRIDE * 2) + k4 * 8)) = u;        \
    }                                                                      \
  }

  // consumer: 16 k-steps x 2 tiles from half-buffer P (R9-verified body)
#define COMPUTE_HALF(P, WSEL, H1, TRANSPOSED)                              \
  {                                                                        \
    const uint4* w0 = wpk + (WSEL)*32768 + (2 * h) * 2048 + (H1)*1024 +    \
                      half * 32 + l31;                                     \
    const uint4* w1 = w0 + 2048;                                           \
    _Pragma("unroll 4") for (int k = 0; k < 16; ++k) {                     \
      uint4 a = ld_lds_64x2(Xs[P], abase + (unsigned)k * 32);              \
      uint4 b0 = w0[k * 64];                                               \
      uint4 b1 = w1[k * 64];                                               \
      if (TRANSPOSED) {                                                    \
        acc0 = mfma32(b0, a, acc0);                                        \
        acc1 = mfma32(b1, a, acc1);                                        \
      } else {                                                             \
        acc0 = mfma32(a, b0, acc0);                                        \
        acc1 = mfma32(a, b1, acc1);                                        \
      }                                                                    \
    }                                                                      \
  }

  f32x16 acc0, acc1;
#pragma unroll
  for (int r = 0; r < 16; ++r) { acc0[r] = 0.0f; acc1[r] = 0.0f; }

  // ---------------- specialized pipeline (6 uniform barriers) -------------
  // prologue: producers stage K half0 -> buf0
  if (prod) PSTAGE(k_in, 0, 0);
  __syncthreads();

  // ph0: producers K half1 -> buf1 | consumers K half0 from buf0 (NORMAL)
  if (prod) { PSTAGE(k_in, 1, 1); } else { COMPUTE_HALF(0, 1, 0, 0); }
  __syncthreads();

  // ph1: producers Q half0 -> buf0 | consumers K half1 from buf1 + K epilogue
  if (prod) {
    PSTAGE(q_in, 0, 0);
  } else {
    COMPUTE_HALF(1, 1, 1, 0);
    char* scr = &SCR[h][0];
    const float bc0 = bk[h * 64 + l31];
    const float bc1 = bk[h * 64 + 32 + l31];
#pragma unroll
    for (int r = 0; r < 16; ++r) {
      const int n = (r & 3) + 8 * (r >> 2) + 4 * half;
      const unsigned base = (unsigned)(n * 128);
      const unsigned sw = (unsigned)(n & 7) << 4;
      *(unsigned short*)(scr + ((base + l31 * 2) ^ sw)) =
          (unsigned short)f2b(acc0[r] + bc0);
      *(unsigned short*)(scr + ((base + 64 + l31 * 2) ^ sw)) =
          (unsigned short)f2b(acc1[r] + bc1);
      acc0[r] = 0.0f;
      acc1[r] = 0.0f;
    }
  }
  __syncthreads();

  // ph2: producers Q half1 -> buf1 | consumers Q half0 from buf0 (TRANSPOSED)
  if (prod) { PSTAGE(q_in, 1, 1); } else { COMPUTE_HALF(0, 0, 0, 1); }
  __syncthreads();

  // ph3: producers V half0 -> buf0 | consumers Q half1 from buf1 + Q epilogue
  if (prod) {
    PSTAGE(v_in, 0, 0);
  } else {
    COMPUTE_HALF(1, 0, 1, 1);
#pragma unroll
    for (int q = 0; q < 8; ++q) {
      const int n0 = ((2 * q) & 3) + 8 * (q >> 1) + 4 * half;  // feature idx
      float2 bv0 = *(const float2*)(bq + h * 64 + n0);
      float2 bv1 = *(const float2*)(bq + h * 64 + 32 + n0);
      QT[0][q] = f2b(acc0[2 * q] + bv0.x) | (f2b(acc0[2 * q + 1] + bv0.y) << 16);
      QT[1][q] = f2b(acc1[2 * q] + bv1.x) | (f2b(acc1[2 * q + 1] + bv1.y) << 16);
      acc0[2 * q] = 0.0f; acc0[2 * q + 1] = 0.0f;
      acc1[2 * q] = 0.0f; acc1[2 * q + 1] = 0.0f;
    }
  }
  __syncthreads();

  // ph4: producers V half1 -> buf1 | consumers V half0 from buf0 (NORMAL)
  if (prod) { PSTAGE(v_in, 1, 1); } else { COMPUTE_HALF(0, 2, 0, 0); }
  __syncthreads();

  // ph5: consumers V half1 from buf1 + V epilogue (producers done; no more
  // barriers below, so producer waves simply fall through and exit)
  if (!prod) {
    COMPUTE_HALF(1, 2, 1, 0);
    const float bc0 = bv[h * 64 + l31];
    const float bc1 = bv[h * 64 + 32 + l31];
#pragma unroll
    for (int q = 0; q < 8; ++q) {
      VP[0][q] = f2b(acc0[2 * q] + bc0) | (f2b(acc0[2 * q + 1] + bc0) << 16);
      VP[1][q] = f2b(acc1[2 * q] + bc1) | (f2b(acc1[2 * q + 1] + bc1) << 16);
    }

    // ---------------- attention (barrier-free, per-wave; R9 verbatim) -----
    char* scr = &SCR[h][0];
    uint4 KA[4];
#pragma unroll
    for (int kk = 0; kk < 4; ++kk) {
      const unsigned off =
          (unsigned)(l31 * 128 + kk * 32 + half * 16) ^ ((unsigned)(l31 & 7) << 4);
      KA[kk] = *(const uint4*)(scr + off);
    }

    // S^T = K * Q^T : lane = query n, regs = key m
    f32x16 lg;
#pragma unroll
    for (int r = 0; r < 16; ++r) lg[r] = 0.0f;
#pragma unroll
    for (int kk = 0; kk < 4; ++kk) {
      uint4 qf = frag_cd(QT[kk >> 1], (kk & 1) * 4, half);
      lg = mfma32(KA[kk], qf, lg);
    }

    // softmax over keys m, in place (lane = query n, regs = key m)
    const float* mrow = mask + (size_t)bs * 32;
    float w[16];
#pragma unroll
    for (int q = 0; q < 8; ++q) {
      const int mm0 = ((2 * q) & 3) + 8 * (q >> 1) + 4 * half;
      float2 mk = *(const float2*)(mrow + mm0);
      w[2 * q] = lg[2 * q] * 0.125f + mk.x;
      w[2 * q + 1] = lg[2 * q + 1] * 0.125f + mk.y;
    }
    float mx = w[0];
#pragma unroll
    for (int r = 1; r < 16; ++r) mx = fmaxf(mx, w[r]);
    mx = fmaxf(mx, __shfl_xor(mx, 32));
    float ss = 0.0f;
#pragma unroll
    for (int r = 0; r < 16; ++r) {
      w[r] = __expf(w[r] - mx);
      ss += w[r];
    }
    ss += __shfl_xor(ss, 32);
    const float inv = __frcp_rn(ss);
#pragma unroll
    for (int r = 0; r < 16; ++r) w[r] *= inv;

    // pack P (lane = query n, reg pairs = key rows)
    unsigned PP[8];
#pragma unroll
    for (int q = 0; q < 8; ++q)
      PP[q] = f2b(w[2 * q]) | (f2b(w[2 * q + 1]) << 16);

    // out_w: transpose through per-head scratch (K-buf dead by data dep)
    asm volatile("" ::: "memory");
    float* scrF = (float*)scr;  // 32 x 33 floats = 4224 B
#pragma unroll
    for (int r = 0; r < 16; ++r) {
      const int mm = (r & 3) + 8 * (r >> 2) + 4 * half;
      scrF[l31 * 33 + mm] = w[r];  // [query n=l31][key mm]
    }
    const int b = bs >> 9;
    const int s = bs & 511;
    float* wout = out_w + ((size_t)((b * 8 + h) * 512 + s)) * 1024;
#pragma unroll
    for (int j = 0; j < 16; ++j) {
      const int n = 2 * j + half;
      wout[n * 32 + l31] = scrF[n * 33 + l31];
    }

    // O = P * V
    f32x16 o0, o1;
#pragma unroll
    for (int r = 0; r < 16; ++r) { o0[r] = 0.0f; o1[r] = 0.0f; }
#pragma unroll
    for (int kk = 0; kk < 2; ++kk) {
      uint4 pa = frag_cd(PP, 4 * kk, half);
      uint4 vb0 = frag_cd(VP[0], 4 * kk, half);
      uint4 vb1 = frag_cd(VP[1], 4 * kk, half);
      o0 = mfma32(pa, vb0, o0);
      o1 = mfma32(pa, vb1, o1);
    }

    // output: lane col d = t*32+l31 of head h, rows n in regs
    float* obase = out_attn + (size_t)bs * NBD + h * 64 + l31;
#pragma unroll
    for (int r = 0; r < 16; ++r) {
      const int n = (r & 3) + 8 * (r >> 2) + 4 * half;
      obase[n * 512] = o0[r];
      obase[n * 512 + 32] = o1[r];
    }
  }
#undef PSTAGE
#undef COMPUTE_HALF
}

extern "C" void kernel_launch(void* const* d_in, const int* in_sizes, int n_in,
                              void* d_out, int out_size, void* d_ws, size_t ws_size,
                              hipStream_t stream) {
  const float* q    = (const float*)d_in[0];
  const float* k    = (const float*)d_in[1];
  const float* v    = (const float*)d_in[2];
  const float* mask = (const float*)d_in[3];
  const float* wq   = (const float*)d_in[4];
  const float* bq   = (const float*)d_in[5];
  const float* wk   = (const float*)d_in[6];
  const float* bk   = (const float*)d_in[7];
  const float* wv   = (const float*)d_in[8];
  const float* bv   = (const float*)d_in[9];

  uint4* wpk = (uint4*)d_ws;  // 3*32768 uint4 = 1.5 MB fragment-major weights
  float* out_attn = (float*)d_out;
  float* out_w = out_attn + (size_t)4 * 512 * 32 * 512;

  wconv_kernel<<<384, 256, 0, stream>>>(wq, wk, wv, wpk);
  mhba_kernel<<<2048, 768, 0, stream>>>(q, k, v, mask, bq, bk, bv, wpk,
                                        out_attn, out_w);
}

// Round 17
// 218.023 us; speedup vs baseline: 2.4934x; 1.3069x over previous
//
#include <hip/hip_runtime.h>
#include <hip/hip_bf16.h>

// MultiheadBlockAttention: B=4, S=512, NB=32, D=512, H=8, dh=64.
// R17 = R13 (best: SMUL=2, launch_bounds(512,2), async T14 staging, 231us,
// spill-free) + two micro-opts:
//   - f2b via __float2bfloat16 (RNE): compiler emits v_cvt_pk_bf16_f32 for
//     packed pairs (manual bit-math was ~4 VALU/convert and un-fusable, m240)
//   - COMPUTE unroll 4 -> 8: 16 outstanding weight loads (was 8) for MLP;
//     ~130 regs of headroom at the 256 cap (R14's spill was full-unroll at
//     a 128 cap -- different regime). Tripwire: WRITE>260MB => spill.

#define NBD (32 * 512)
#define XH_STRIDE 260                   // shorts per half-row = 520 B
#define XH_BYTES (32 * XH_STRIDE * 2)   // 16640 B per (bs) half-slice

typedef __bf16 bf16x8 __attribute__((ext_vector_type(8)));
typedef float f32x16 __attribute__((ext_vector_type(16)));

__device__ __forceinline__ unsigned f2b(float f) {
  union { __hip_bfloat16 h; unsigned short u; } c;
  c.h = __float2bfloat16(f);  // RNE, same numerics as prior bit-math
  return (unsigned)c.u;
}

__device__ __forceinline__ f32x16 mfma32(uint4 a, uint4 b, f32x16 c) {
  union { uint4 u; bf16x8 v; } ua, ub;
  ua.u = a;
  ub.u = b;
  return __builtin_amdgcn_mfma_f32_32x32x16_bf16(ua.v, ub.v, c, 0, 0, 0);
}

// two ds_read_b64 (8-aligned base)
__device__ __forceinline__ uint4 ld_lds_64x2(const unsigned short* p, unsigned byteoff) {
  const char* c = (const char*)p;
  uint2 lo = *(const uint2*)(c + byteoff);
  uint2 hi = *(const uint2*)(c + byteoff + 8);
  uint4 r;
  r.x = lo.x; r.y = lo.y; r.z = hi.x; r.w = hi.y;
  return r;
}

// C/D packed frag -> A/B-frag k-slice [qb block]: cross-half exchange + select.
__device__ __forceinline__ uint4 frag_cd(const unsigned* CP, int qb, int half) {
  const unsigned s0 = __shfl_xor(CP[qb + 0], 32);
  const unsigned s1 = __shfl_xor(CP[qb + 1], 32);
  const unsigned s2 = __shfl_xor(CP[qb + 2], 32);
  const unsigned s3 = __shfl_xor(CP[qb + 3], 32);
  uint4 f;
  f.x = half ? s2 : CP[qb + 0];
  f.y = half ? s3 : CP[qb + 1];
  f.z = half ? CP[qb + 2] : s0;
  f.w = half ? CP[qb + 3] : s1;
  return f;
}

// Pack wq|wk|wv fragment-major bf16: uint4 index
//   m*32768 + tile*2048 + k*64 + half*32 + l31  holds W[tile*32+l31][k*16+half*8..+7]
__global__ void wconv_kernel(const float* __restrict__ wq,
                             const float* __restrict__ wk,
                             const float* __restrict__ wv,
                             uint4* __restrict__ out) {
  const int g = blockIdx.x * blockDim.x + threadIdx.x;  // 0..98303
  const int m = g >> 15;
  const int j = g & 32767;
  const int l31 = j & 31;
  const int half = (j >> 5) & 1;
  const int k = (j >> 6) & 31;
  const int tile = j >> 11;  // 0..15
  const float* src = (m == 0) ? wq : (m == 1) ? wk : wv;
  const float4* p = (const float4*)(src + (size_t)(tile * 32 + l31) * 512 + k * 16 + half * 8);
  float4 f0 = p[0], f1 = p[1];
  uint4 o;
  o.x = f2b(f0.x) | (f2b(f0.y) << 16);
  o.y = f2b(f0.z) | (f2b(f0.w) << 16);
  o.z = f2b(f1.x) | (f2b(f1.y) << 16);
  o.w = f2b(f1.z) | (f2b(f1.w) << 16);
  out[g] = o;
}

__global__ __launch_bounds__(512, 2)
void mhba_kernel(const float* __restrict__ q_in, const float* __restrict__ k_in,
                 const float* __restrict__ v_in, const float* __restrict__ mask,
                 const float* __restrict__ bq, const float* __restrict__ bk,
                 const float* __restrict__ bv,
                 const uint4* __restrict__ wpk,   // fragment-major bf16 weights
                 float* __restrict__ out_attn,    // [B,S,NB,D]
                 float* __restrict__ out_w) {     // [B,H,S,NB,NB]
  // Double-buffered half-tiles, both bs: [buf][bs j at j*XH_BYTES].
  __shared__ unsigned short Xs[2][2 * 32 * XH_STRIDE];  // 66560 B
  __shared__ __align__(16) char SCR[8][2][4352];        // 69632 B

  const int bs0 = blockIdx.x * 2;
  const int tid = threadIdx.x;  // 0..511
  const int lane = tid & 63;
  const int h = tid >> 6;       // wave == head
  const int l31 = lane & 31;
  const int half = lane >> 5;

  const float* srcs[3] = {k_in, q_in, v_in};  // m-order: K, Q, V

  unsigned QT[2][2][8], VP[2][2][8];  // [bs j][tile t][q]
  const unsigned abase = (unsigned)(l31 * (XH_STRIDE * 2) + half * 16);

  float4 st[8];  // raw in-flight staging regs (32) -- no dependent op until
                 // STAGE_WRITE, so loads overlap the 64-MFMA COMPUTE phase.

  // issue the 8 loads for (matrix M, feature-half H1), both bs; NO conversion
#define STAGE_LOAD(M, H1)                                                  \
  {                                                                        \
    _Pragma("unroll") for (int j = 0; j < 2; ++j) {                        \
      const float4* s4 = (const float4*)(srcs[M] + (size_t)(bs0 + j) * NBD);\
      _Pragma("unroll") for (int i = 0; i < 4; ++i) {                      \
        const int idx4 = i * 512 + tid;                                    \
        st[j * 4 + i] = s4[(idx4 >> 6) * 128 + (H1)*64 + (idx4 & 63)];     \
      }                                                                    \
    }                                                                      \
  }

  // convert + write staged regs into half-buffer P (both bs) -- after COMPUTE
#define STAGE_WRITE(P)                                                     \
  {                                                                        \
    _Pragma("unroll") for (int j = 0; j < 2; ++j) {                        \
      _Pragma("unroll") for (int i = 0; i < 4; ++i) {                      \
        const int idx4 = i * 512 + tid;                                    \
        const int n = idx4 >> 6, k4 = idx4 & 63;                           \
        float4 f = st[j * 4 + i];                                          \
        uint2 u;                                                           \
        u.x = f2b(f.x) | (f2b(f.y) << 16);                                 \
        u.y = f2b(f.z) | (f2b(f.w) << 16);                                 \
        *(uint2*)((char*)Xs[P] + (j * XH_BYTES + n * (XH_STRIDE * 2) + k4 * 8)) = u; \
      }                                                                    \
    }                                                                      \
  }

  // 16 k-steps from half-buffer P; weight frags shared across bs ->
  // 4 MFMAs per 2 weight loads. accJT: bs j, tile t.
#define COMPUTE_HALF(P, WSEL, H1, TRANSPOSED)                              \
  {                                                                        \
    const uint4* w0 = wpk + (WSEL)*32768 + (2 * h) * 2048 + (H1)*1024 +    \
                      half * 32 + l31;                                     \
    const uint4* w1 = w0 + 2048;                                           \
    _Pragma("unroll 8") for (int k = 0; k < 16; ++k) {                     \
      uint4 b0 = w0[k * 64];                                               \
      uint4 b1 = w1[k * 64];                                               \
      uint4 a0 = ld_lds_64x2(Xs[P], abase + (unsigned)k * 32);             \
      uint4 a1 = ld_lds_64x2(Xs[P], XH_BYTES + abase + (unsigned)k * 32);  \
      if (TRANSPOSED) {                                                    \
        acc00 = mfma32(b0, a0, acc00);                                     \
        acc01 = mfma32(b1, a0, acc01);                                     \
        acc10 = mfma32(b0, a1, acc10);                                     \
        acc11 = mfma32(b1, a1, acc11);                                     \
      } else {                                                             \
        acc00 = mfma32(a0, b0, acc00);                                     \
        acc01 = mfma32(a0, b1, acc01);                                     \
        acc10 = mfma32(a1, b0, acc10);                                     \
        acc11 = mfma32(a1, b1, acc11);                                     \
      }                                                                    \
    }                                                                      \
  }

#define RESET_ACCS                                                         \
  {                                                                        \
    _Pragma("unroll") for (int r = 0; r < 16; ++r) {                       \
      acc00[r] = 0.0f; acc01[r] = 0.0f; acc10[r] = 0.0f; acc11[r] = 0.0f;  \
    }                                                                      \
  }

  f32x16 acc00, acc01, acc10, acc11;
  RESET_ACCS;

  // ---------------- pipelined projections (async feature-split) -----------
  STAGE_LOAD(0, 0);
  STAGE_WRITE(0);
  __syncthreads();

  // ph0: K half0 from buf0 (NORMAL), stage K half1 -> buf1
  STAGE_LOAD(0, 1);
  COMPUTE_HALF(0, 1, 0, 0);
  STAGE_WRITE(1);
  __syncthreads();

  // ph1: K half1 from buf1 (NORMAL), stage Q half0 -> buf0
  STAGE_LOAD(1, 0);
  COMPUTE_HALF(1, 1, 1, 0);
  {  // K epilogue per bs (normal C/D: lane = feature col, regs = token rows)
    const float bc0 = bk[h * 64 + l31];
    const float bc1 = bk[h * 64 + 32 + l31];
#pragma unroll
    for (int j = 0; j < 2; ++j) {
      char* scr = &SCR[h][j][0];
#pragma unroll
      for (int r = 0; r < 16; ++r) {
        const int n = (r & 3) + 8 * (r >> 2) + 4 * half;
        const unsigned base = (unsigned)(n * 128);
        const unsigned sw = (unsigned)(n & 7) << 4;
        const float a0 = (j == 0) ? acc00[r] : acc10[r];
        const float a1 = (j == 0) ? acc01[r] : acc11[r];
        *(unsigned short*)(scr + ((base + l31 * 2) ^ sw)) =
            (unsigned short)f2b(a0 + bc0);
        *(unsigned short*)(scr + ((base + 64 + l31 * 2) ^ sw)) =
            (unsigned short)f2b(a1 + bc1);
      }
    }
    RESET_ACCS;
  }
  STAGE_WRITE(0);
  __syncthreads();

  // ph2: Q half0 from buf0 (TRANSPOSED), stage Q half1 -> buf1
  STAGE_LOAD(1, 1);
  COMPUTE_HALF(0, 0, 0, 1);
  STAGE_WRITE(1);
  __syncthreads();

  // ph3: Q half1 from buf1 (TRANSPOSED), stage V half0 -> buf0
  STAGE_LOAD(2, 0);
  COMPUTE_HALF(1, 0, 1, 1);
  {  // Q^T epilogue: lane = token, regs = features
#pragma unroll
    for (int q = 0; q < 8; ++q) {
      const int n0 = ((2 * q) & 3) + 8 * (q >> 1) + 4 * half;  // feature idx
      float2 b0 = *(const float2*)(bq + h * 64 + n0);
      float2 b1 = *(const float2*)(bq + h * 64 + 32 + n0);
      QT[0][0][q] = f2b(acc00[2 * q] + b0.x) | (f2b(acc00[2 * q + 1] + b0.y) << 16);
      QT[0][1][q] = f2b(acc01[2 * q] + b1.x) | (f2b(acc01[2 * q + 1] + b1.y) << 16);
      QT[1][0][q] = f2b(acc10[2 * q] + b0.x) | (f2b(acc10[2 * q + 1] + b0.y) << 16);
      QT[1][1][q] = f2b(acc11[2 * q] + b1.x) | (f2b(acc11[2 * q + 1] + b1.y) << 16);
    }
    RESET_ACCS;
  }
  STAGE_WRITE(0);
  __syncthreads();

  // ph4: V half0 from buf0 (NORMAL), stage V half1 -> buf1
  STAGE_LOAD(2, 1);
  COMPUTE_HALF(0, 2, 0, 0);
  STAGE_WRITE(1);
  __syncthreads();

  // ph5: V half1 from buf1 (NORMAL, no staging)
  COMPUTE_HALF(1, 2, 1, 0);
  {  // V epilogue: lane = feature col, regs = token rows
    const float bc0 = bv[h * 64 + l31];
    const float bc1 = bv[h * 64 + 32 + l31];
#pragma unroll
    for (int q = 0; q < 8; ++q) {
      VP[0][0][q] = f2b(acc00[2 * q] + bc0) | (f2b(acc00[2 * q + 1] + bc0) << 16);
      VP[0][1][q] = f2b(acc01[2 * q] + bc1) | (f2b(acc01[2 * q + 1] + bc1) << 16);
      VP[1][0][q] = f2b(acc10[2 * q] + bc0) | (f2b(acc10[2 * q + 1] + bc0) << 16);
      VP[1][1][q] = f2b(acc11[2 * q] + bc1) | (f2b(acc11[2 * q + 1] + bc1) << 16);
    }
  }

  // ---------------- attention per bs (barrier-free, per-wave; R10 verbatim)
#pragma unroll
  for (int j = 0; j < 2; ++j) {
    const int bsj = bs0 + j;
    char* scr = &SCR[h][j][0];

    // K A-frags from scratch
    uint4 KA[4];
#pragma unroll
    for (int kk = 0; kk < 4; ++kk) {
      const unsigned off =
          (unsigned)(l31 * 128 + kk * 32 + half * 16) ^ ((unsigned)(l31 & 7) << 4);
      KA[kk] = *(const uint4*)(scr + off);
    }

    // S^T = K * Q^T : lane = query n, regs = key m
    f32x16 lg;
#pragma unroll
    for (int r = 0; r < 16; ++r) lg[r] = 0.0f;
#pragma unroll
    for (int kk = 0; kk < 4; ++kk) {
      uint4 qf = frag_cd(QT[j][kk >> 1], (kk & 1) * 4, half);
      lg = mfma32(KA[kk], qf, lg);
    }

    // softmax over keys m, in place; additive mask
    const float* mrow = mask + (size_t)bsj * 32;
    float w[16];
#pragma unroll
    for (int q = 0; q < 8; ++q) {
      const int mm0 = ((2 * q) & 3) + 8 * (q >> 1) + 4 * half;
      float2 mk = *(const float2*)(mrow + mm0);
      w[2 * q] = lg[2 * q] * 0.125f + mk.x;
      w[2 * q + 1] = lg[2 * q + 1] * 0.125f + mk.y;
    }
    float mx = w[0];
#pragma unroll
    for (int r = 1; r < 16; ++r) mx = fmaxf(mx, w[r]);
    mx = fmaxf(mx, __shfl_xor(mx, 32));
    float ss = 0.0f;
#pragma unroll
    for (int r = 0; r < 16; ++r) {
      w[r] = __expf(w[r] - mx);
      ss += w[r];
    }
    ss += __shfl_xor(ss, 32);
    const float inv = __frcp_rn(ss);
#pragma unroll
    for (int r = 0; r < 16; ++r) w[r] *= inv;

    // pack P (lane = query n, reg pairs = key rows)
    unsigned PP[8];
#pragma unroll
    for (int q = 0; q < 8; ++q)
      PP[q] = f2b(w[2 * q]) | (f2b(w[2 * q + 1]) << 16);

    // out_w: transpose through scratch j (K-buf dead by data dependence)
    asm volatile("" ::: "memory");
    float* scrF = (float*)scr;  // 32 x 33 floats = 4224 B <= 4352
#pragma unroll
    for (int r = 0; r < 16; ++r) {
      const int mm = (r & 3) + 8 * (r >> 2) + 4 * half;
      scrF[l31 * 33 + mm] = w[r];  // [query n=l31][key mm]
    }
    const int b = bsj >> 9;
    const int s = bsj & 511;
    float* wout = out_w + ((size_t)((b * 8 + h) * 512 + s)) * 1024;
#pragma unroll
    for (int jj = 0; jj < 16; ++jj) {
      const int n = 2 * jj + half;
      wout[n * 32 + l31] = scrF[n * 33 + l31];
    }

    // O = P * V
    f32x16 o0, o1;
#pragma unroll
    for (int r = 0; r < 16; ++r) { o0[r] = 0.0f; o1[r] = 0.0f; }
#pragma unroll
    for (int kk = 0; kk < 2; ++kk) {
      uint4 pa = frag_cd(PP, 4 * kk, half);
      uint4 vb0 = frag_cd(VP[j][0], 4 * kk, half);
      uint4 vb1 = frag_cd(VP[j][1], 4 * kk, half);
      o0 = mfma32(pa, vb0, o0);
      o1 = mfma32(pa, vb1, o1);
    }

    // output: lane col d = t*32+l31 of head h, rows n in regs
    float* obase = out_attn + (size_t)bsj * NBD + h * 64 + l31;
#pragma unroll
    for (int r = 0; r < 16; ++r) {
      const int n = (r & 3) + 8 * (r >> 2) + 4 * half;
      obase[n * 512] = o0[r];
      obase[n * 512 + 32] = o1[r];
    }
  }
#undef STAGE_LOAD
#undef STAGE_WRITE
#undef COMPUTE_HALF
#undef RESET_ACCS
}

extern "C" void kernel_launch(void* const* d_in, const int* in_sizes, int n_in,
                              void* d_out, int out_size, void* d_ws, size_t ws_size,
                              hipStream_t stream) {
  const float* q    = (const float*)d_in[0];
  const float* k    = (const float*)d_in[1];
  const float* v    = (const float*)d_in[2];
  const float* mask = (const float*)d_in[3];
  const float* wq   = (const float*)d_in[4];
  const float* bq   = (const float*)d_in[5];
  const float* wk   = (const float*)d_in[6];
  const float* bk   = (const float*)d_in[7];
  const float* wv   = (const float*)d_in[8];
  const float* bv   = (const float*)d_in[9];

  uint4* wpk = (uint4*)d_ws;  // 3*32768 uint4 = 1.5 MB fragment-major weights
  float* out_attn = (float*)d_out;
  float* out_w = out_attn + (size_t)4 * 512 * 32 * 512;

  wconv_kernel<<<384, 256, 0, stream>>>(wq, wk, wv, wpk);
  mhba_kernel<<<1024, 512, 0, stream>>>(q, k, v, mask, bq, bk, bv, wpk,
                                        out_attn, out_w);
}

// Round 18
// 217.552 us; speedup vs baseline: 2.4988x; 1.0022x over previous
//
#include <hip/hip_runtime.h>
#include <hip/hip_bf16.h>

// MultiheadBlockAttention: B=4, S=512, NB=32, D=512, H=8, dh=64.
// R18 = R17 (best: SMUL=2, launch_bounds(512,2), async T14 staging, cvt_pk
// f2b, unroll 8 -- 218us, spill-free) + frag_cd via v_permlane32_swap_b32:
// one instruction exchanges a.hi<->b.lo across the lane-32 split and returns
// BOTH results, replacing 4 shfl_xor (ds_permute: LDS pipe + lgkmcnt) +
// 4 v_cndmask per fragment with 2 VALU ops. ~20 fragments/thread.

#define NBD (32 * 512)
#define XH_STRIDE 260                   // shorts per half-row = 520 B
#define XH_BYTES (32 * XH_STRIDE * 2)   // 16640 B per (bs) half-slice

typedef __bf16 bf16x8 __attribute__((ext_vector_type(8)));
typedef float f32x16 __attribute__((ext_vector_type(16)));

__device__ __forceinline__ unsigned f2b(float f) {
  union { __hip_bfloat16 h; unsigned short u; } c;
  c.h = __float2bfloat16(f);  // RNE
  return (unsigned)c.u;
}

__device__ __forceinline__ f32x16 mfma32(uint4 a, uint4 b, f32x16 c) {
  union { uint4 u; bf16x8 v; } ua, ub;
  ua.u = a;
  ub.u = b;
  return __builtin_amdgcn_mfma_f32_32x32x16_bf16(ua.v, ub.v, c, 0, 0, 0);
}

// two ds_read_b64 (8-aligned base)
__device__ __forceinline__ uint4 ld_lds_64x2(const unsigned short* p, unsigned byteoff) {
  const char* c = (const char*)p;
  uint2 lo = *(const uint2*)(c + byteoff);
  uint2 hi = *(const uint2*)(c + byteoff + 8);
  uint4 r;
  r.x = lo.x; r.y = lo.y; r.z = hi.x; r.w = hi.y;
  return r;
}

// C/D packed frag -> A/B-frag k-slice [qb block]: exchange halves across the
// lane-32 split. permlane32_swap(a,b) -> r0={a.lo,b.lo}, r1={a.hi,b.hi}:
//   f.x = r0(CP0,CP2), f.z = r1(CP0,CP2); f.y/f.w from (CP1,CP3).
// (Matches the shfl_xor+cndmask truth table for both halves.)
#if defined(__has_builtin)
#if __has_builtin(__builtin_amdgcn_permlane32_swap)
#define HAVE_PLSWAP 1
#endif
#endif

__device__ __forceinline__ uint4 frag_cd(const unsigned* CP, int qb, int half) {
#ifdef HAVE_PLSWAP
  typedef unsigned uint2v __attribute__((ext_vector_type(2)));
  uint2v r02 = __builtin_amdgcn_permlane32_swap(CP[qb + 0], CP[qb + 2], false, false);
  uint2v r13 = __builtin_amdgcn_permlane32_swap(CP[qb + 1], CP[qb + 3], false, false);
  uint4 f;
  f.x = r02[0];
  f.y = r13[0];
  f.z = r02[1];
  f.w = r13[1];
  return f;
#else
  const unsigned s0 = __shfl_xor(CP[qb + 0], 32);
  const unsigned s1 = __shfl_xor(CP[qb + 1], 32);
  const unsigned s2 = __shfl_xor(CP[qb + 2], 32);
  const unsigned s3 = __shfl_xor(CP[qb + 3], 32);
  uint4 f;
  f.x = half ? s2 : CP[qb + 0];
  f.y = half ? s3 : CP[qb + 1];
  f.z = half ? CP[qb + 2] : s0;
  f.w = half ? CP[qb + 3] : s1;
  return f;
#endif
}

// Pack wq|wk|wv fragment-major bf16: uint4 index
//   m*32768 + tile*2048 + k*64 + half*32 + l31  holds W[tile*32+l31][k*16+half*8..+7]
__global__ void wconv_kernel(const float* __restrict__ wq,
                             const float* __restrict__ wk,
                             const float* __restrict__ wv,
                             uint4* __restrict__ out) {
  const int g = blockIdx.x * blockDim.x + threadIdx.x;  // 0..98303
  const int m = g >> 15;
  const int j = g & 32767;
  const int l31 = j & 31;
  const int half = (j >> 5) & 1;
  const int k = (j >> 6) & 31;
  const int tile = j >> 11;  // 0..15
  const float* src = (m == 0) ? wq : (m == 1) ? wk : wv;
  const float4* p = (const float4*)(src + (size_t)(tile * 32 + l31) * 512 + k * 16 + half * 8);
  float4 f0 = p[0], f1 = p[1];
  uint4 o;
  o.x = f2b(f0.x) | (f2b(f0.y) << 16);
  o.y = f2b(f0.z) | (f2b(f0.w) << 16);
  o.z = f2b(f1.x) | (f2b(f1.y) << 16);
  o.w = f2b(f1.z) | (f2b(f1.w) << 16);
  out[g] = o;
}

__global__ __launch_bounds__(512, 2)
void mhba_kernel(const float* __restrict__ q_in, const float* __restrict__ k_in,
                 const float* __restrict__ v_in, const float* __restrict__ mask,
                 const float* __restrict__ bq, const float* __restrict__ bk,
                 const float* __restrict__ bv,
                 const uint4* __restrict__ wpk,   // fragment-major bf16 weights
                 float* __restrict__ out_attn,    // [B,S,NB,D]
                 float* __restrict__ out_w) {     // [B,H,S,NB,NB]
  // Double-buffered half-tiles, both bs: [buf][bs j at j*XH_BYTES].
  __shared__ unsigned short Xs[2][2 * 32 * XH_STRIDE];  // 66560 B
  __shared__ __align__(16) char SCR[8][2][4352];        // 69632 B

  const int bs0 = blockIdx.x * 2;
  const int tid = threadIdx.x;  // 0..511
  const int lane = tid & 63;
  const int h = tid >> 6;       // wave == head
  const int l31 = lane & 31;
  const int half = lane >> 5;

  const float* srcs[3] = {k_in, q_in, v_in};  // m-order: K, Q, V

  unsigned QT[2][2][8], VP[2][2][8];  // [bs j][tile t][q]
  const unsigned abase = (unsigned)(l31 * (XH_STRIDE * 2) + half * 16);

  float4 st[8];  // raw in-flight staging regs (32) -- no dependent op until
                 // STAGE_WRITE, so loads overlap the 64-MFMA COMPUTE phase.

  // issue the 8 loads for (matrix M, feature-half H1), both bs; NO conversion
#define STAGE_LOAD(M, H1)                                                  \
  {                                                                        \
    _Pragma("unroll") for (int j = 0; j < 2; ++j) {                        \
      const float4* s4 = (const float4*)(srcs[M] + (size_t)(bs0 + j) * NBD);\
      _Pragma("unroll") for (int i = 0; i < 4; ++i) {                      \
        const int idx4 = i * 512 + tid;                                    \
        st[j * 4 + i] = s4[(idx4 >> 6) * 128 + (H1)*64 + (idx4 & 63)];     \
      }                                                                    \
    }                                                                      \
  }

  // convert + write staged regs into half-buffer P (both bs) -- after COMPUTE
#define STAGE_WRITE(P)                                                     \
  {                                                                        \
    _Pragma("unroll") for (int j = 0; j < 2; ++j) {                        \
      _Pragma("unroll") for (int i = 0; i < 4; ++i) {                      \
        const int idx4 = i * 512 + tid;                                    \
        const int n = idx4 >> 6, k4 = idx4 & 63;                           \
        float4 f = st[j * 4 + i];                                          \
        uint2 u;                                                           \
        u.x = f2b(f.x) | (f2b(f.y) << 16);                                 \
        u.y = f2b(f.z) | (f2b(f.w) << 16);                                 \
        *(uint2*)((char*)Xs[P] + (j * XH_BYTES + n * (XH_STRIDE * 2) + k4 * 8)) = u; \
      }                                                                    \
    }                                                                      \
  }

  // 16 k-steps from half-buffer P; weight frags shared across bs ->
  // 4 MFMAs per 2 weight loads. accJT: bs j, tile t.
#define COMPUTE_HALF(P, WSEL, H1, TRANSPOSED)                              \
  {                                                                        \
    const uint4* w0 = wpk + (WSEL)*32768 + (2 * h) * 2048 + (H1)*1024 +    \
                      half * 32 + l31;                                     \
    const uint4* w1 = w0 + 2048;                                           \
    _Pragma("unroll 8") for (int k = 0; k < 16; ++k) {                     \
      uint4 b0 = w0[k * 64];                                               \
      uint4 b1 = w1[k * 64];                                               \
      uint4 a0 = ld_lds_64x2(Xs[P], abase + (unsigned)k * 32);             \
      uint4 a1 = ld_lds_64x2(Xs[P], XH_BYTES + abase + (unsigned)k * 32);  \
      if (TRANSPOSED) {                                                    \
        acc00 = mfma32(b0, a0, acc00);                                     \
        acc01 = mfma32(b1, a0, acc01);                                     \
        acc10 = mfma32(b0, a1, acc10);                                     \
        acc11 = mfma32(b1, a1, acc11);                                     \
      } else {                                                             \
        acc00 = mfma32(a0, b0, acc00);                                     \
        acc01 = mfma32(a0, b1, acc01);                                     \
        acc10 = mfma32(a1, b0, acc10);                                     \
        acc11 = mfma32(a1, b1, acc11);                                     \
      }                                                                    \
    }                                                                      \
  }

#define RESET_ACCS                                                         \
  {                                                                        \
    _Pragma("unroll") for (int r = 0; r < 16; ++r) {                       \
      acc00[r] = 0.0f; acc01[r] = 0.0f; acc10[r] = 0.0f; acc11[r] = 0.0f;  \
    }                                                                      \
  }

  f32x16 acc00, acc01, acc10, acc11;
  RESET_ACCS;

  // ---------------- pipelined projections (async feature-split) -----------
  STAGE_LOAD(0, 0);
  STAGE_WRITE(0);
  __syncthreads();

  // ph0: K half0 from buf0 (NORMAL), stage K half1 -> buf1
  STAGE_LOAD(0, 1);
  COMPUTE_HALF(0, 1, 0, 0);
  STAGE_WRITE(1);
  __syncthreads();

  // ph1: K half1 from buf1 (NORMAL), stage Q half0 -> buf0
  STAGE_LOAD(1, 0);
  COMPUTE_HALF(1, 1, 1, 0);
  {  // K epilogue per bs (normal C/D: lane = feature col, regs = token rows)
    const float bc0 = bk[h * 64 + l31];
    const float bc1 = bk[h * 64 + 32 + l31];
#pragma unroll
    for (int j = 0; j < 2; ++j) {
      char* scr = &SCR[h][j][0];
#pragma unroll
      for (int r = 0; r < 16; ++r) {
        const int n = (r & 3) + 8 * (r >> 2) + 4 * half;
        const unsigned base = (unsigned)(n * 128);
        const unsigned sw = (unsigned)(n & 7) << 4;
        const float a0 = (j == 0) ? acc00[r] : acc10[r];
        const float a1 = (j == 0) ? acc01[r] : acc11[r];
        *(unsigned short*)(scr + ((base + l31 * 2) ^ sw)) =
            (unsigned short)f2b(a0 + bc0);
        *(unsigned short*)(scr + ((base + 64 + l31 * 2) ^ sw)) =
            (unsigned short)f2b(a1 + bc1);
      }
    }
    RESET_ACCS;
  }
  STAGE_WRITE(0);
  __syncthreads();

  // ph2: Q half0 from buf0 (TRANSPOSED), stage Q half1 -> buf1
  STAGE_LOAD(1, 1);
  COMPUTE_HALF(0, 0, 0, 1);
  STAGE_WRITE(1);
  __syncthreads();

  // ph3: Q half1 from buf1 (TRANSPOSED), stage V half0 -> buf0
  STAGE_LOAD(2, 0);
  COMPUTE_HALF(1, 0, 1, 1);
  {  // Q^T epilogue: lane = token, regs = features
#pragma unroll
    for (int q = 0; q < 8; ++q) {
      const int n0 = ((2 * q) & 3) + 8 * (q >> 1) + 4 * half;  // feature idx
      float2 b0 = *(const float2*)(bq + h * 64 + n0);
      float2 b1 = *(const float2*)(bq + h * 64 + 32 + n0);
      QT[0][0][q] = f2b(acc00[2 * q] + b0.x) | (f2b(acc00[2 * q + 1] + b0.y) << 16);
      QT[0][1][q] = f2b(acc01[2 * q] + b1.x) | (f2b(acc01[2 * q + 1] + b1.y) << 16);
      QT[1][0][q] = f2b(acc10[2 * q] + b0.x) | (f2b(acc10[2 * q + 1] + b0.y) << 16);
      QT[1][1][q] = f2b(acc11[2 * q] + b1.x) | (f2b(acc11[2 * q + 1] + b1.y) << 16);
    }
    RESET_ACCS;
  }
  STAGE_WRITE(0);
  __syncthreads();

  // ph4: V half0 from buf0 (NORMAL), stage V half1 -> buf1
  STAGE_LOAD(2, 1);
  COMPUTE_HALF(0, 2, 0, 0);
  STAGE_WRITE(1);
  __syncthreads();

  // ph5: V half1 from buf1 (NORMAL, no staging)
  COMPUTE_HALF(1, 2, 1, 0);
  {  // V epilogue: lane = feature col, regs = token rows
    const float bc0 = bv[h * 64 + l31];
    const float bc1 = bv[h * 64 + 32 + l31];
#pragma unroll
    for (int q = 0; q < 8; ++q) {
      VP[0][0][q] = f2b(acc00[2 * q] + bc0) | (f2b(acc00[2 * q + 1] + bc0) << 16);
      VP[0][1][q] = f2b(acc01[2 * q] + bc1) | (f2b(acc01[2 * q + 1] + bc1) << 16);
      VP[1][0][q] = f2b(acc10[2 * q] + bc0) | (f2b(acc10[2 * q + 1] + bc0) << 16);
      VP[1][1][q] = f2b(acc11[2 * q] + bc1) | (f2b(acc11[2 * q + 1] + bc1) << 16);
    }
  }

  // ---------------- attention per bs (barrier-free, per-wave; R10 verbatim)
#pragma unroll
  for (int j = 0; j < 2; ++j) {
    const int bsj = bs0 + j;
    char* scr = &SCR[h][j][0];

    // K A-frags from scratch
    uint4 KA[4];
#pragma unroll
    for (int kk = 0; kk < 4; ++kk) {
      const unsigned off =
          (unsigned)(l31 * 128 + kk * 32 + half * 16) ^ ((unsigned)(l31 & 7) << 4);
      KA[kk] = *(const uint4*)(scr + off);
    }

    // S^T = K * Q^T : lane = query n, regs = key m
    f32x16 lg;
#pragma unroll
    for (int r = 0; r < 16; ++r) lg[r] = 0.0f;
#pragma unroll
    for (int kk = 0; kk < 4; ++kk) {
      uint4 qf = frag_cd(QT[j][kk >> 1], (kk & 1) * 4, half);
      lg = mfma32(KA[kk], qf, lg);
    }

    // softmax over keys m, in place; additive mask
    const float* mrow = mask + (size_t)bsj * 32;
    float w[16];
#pragma unroll
    for (int q = 0; q < 8; ++q) {
      const int mm0 = ((2 * q) & 3) + 8 * (q >> 1) + 4 * half;
      float2 mk = *(const float2*)(mrow + mm0);
      w[2 * q] = lg[2 * q] * 0.125f + mk.x;
      w[2 * q + 1] = lg[2 * q + 1] * 0.125f + mk.y;
    }
    float mx = w[0];
#pragma unroll
    for (int r = 1; r < 16; ++r) mx = fmaxf(mx, w[r]);
    mx = fmaxf(mx, __shfl_xor(mx, 32));
    float ss = 0.0f;
#pragma unroll
    for (int r = 0; r < 16; ++r) {
      w[r] = __expf(w[r] - mx);
      ss += w[r];
    }
    ss += __shfl_xor(ss, 32);
    const float inv = __frcp_rn(ss);
#pragma unroll
    for (int r = 0; r < 16; ++r) w[r] *= inv;

    // pack P (lane = query n, reg pairs = key rows)
    unsigned PP[8];
#pragma unroll
    for (int q = 0; q < 8; ++q)
      PP[q] = f2b(w[2 * q]) | (f2b(w[2 * q + 1]) << 16);

    // out_w: transpose through scratch j (K-buf dead by data dependence)
    asm volatile("" ::: "memory");
    float* scrF = (float*)scr;  // 32 x 33 floats = 4224 B <= 4352
#pragma unroll
    for (int r = 0; r < 16; ++r) {
      const int mm = (r & 3) + 8 * (r >> 2) + 4 * half;
      scrF[l31 * 33 + mm] = w[r];  // [query n=l31][key mm]
    }
    const int b = bsj >> 9;
    const int s = bsj & 511;
    float* wout = out_w + ((size_t)((b * 8 + h) * 512 + s)) * 1024;
#pragma unroll
    for (int jj = 0; jj < 16; ++jj) {
      const int n = 2 * jj + half;
      wout[n * 32 + l31] = scrF[n * 33 + l31];
    }

    // O = P * V
    f32x16 o0, o1;
#pragma unroll
    for (int r = 0; r < 16; ++r) { o0[r] = 0.0f; o1[r] = 0.0f; }
#pragma unroll
    for (int kk = 0; kk < 2; ++kk) {
      uint4 pa = frag_cd(PP, 4 * kk, half);
      uint4 vb0 = frag_cd(VP[j][0], 4 * kk, half);
      uint4 vb1 = frag_cd(VP[j][1], 4 * kk, half);
      o0 = mfma32(pa, vb0, o0);
      o1 = mfma32(pa, vb1, o1);
    }

    // output: lane col d = t*32+l31 of head h, rows n in regs
    float* obase = out_attn + (size_t)bsj * NBD + h * 64 + l31;
#pragma unroll
    for (int r = 0; r < 16; ++r) {
      const int n = (r & 3) + 8 * (r >> 2) + 4 * half;
      obase[n * 512] = o0[r];
      obase[n * 512 + 32] = o1[r];
    }
  }
#undef STAGE_LOAD
#undef STAGE_WRITE
#undef COMPUTE_HALF
#undef RESET_ACCS
}

extern "C" void kernel_launch(void* const* d_in, const int* in_sizes, int n_in,
                              void* d_out, int out_size, void* d_ws, size_t ws_size,
                              hipStream_t stream) {
  const float* q    = (const float*)d_in[0];
  const float* k    = (const float*)d_in[1];
  const float* v    = (const float*)d_in[2];
  const float* mask = (const float*)d_in[3];
  const float* wq   = (const float*)d_in[4];
  const float* bq   = (const float*)d_in[5];
  const float* wk   = (const float*)d_in[6];
  const float* bk   = (const float*)d_in[7];
  const float* wv   = (const float*)d_in[8];
  const float* bv   = (const float*)d_in[9];

  uint4* wpk = (uint4*)d_ws;  // 3*32768 uint4 = 1.5 MB fragment-major weights
  float* out_attn = (float*)d_out;
  float* out_w = out_attn + (size_t)4 * 512 * 32 * 512;

  wconv_kernel<<<384, 256, 0, stream>>>(wq, wk, wv, wpk);
  mhba_kernel<<<1024, 512, 0, stream>>>(q, k, v, mask, bq, bk, bv, wpk,
                                        out_attn, out_w);
}